// Round 21
// baseline (179.422 us; speedup 1.0000x reference)
//
#include <hip/hip_runtime.h>
#include <hip/hip_bf16.h>
#include <math.h>

typedef __attribute__((ext_vector_type(8))) short bf16x8;
typedef __attribute__((ext_vector_type(4))) float f32x4;

// ---------------- helpers ----------------

__device__ __forceinline__ short f2bf(float f) {           // RNE fp32->bf16
    unsigned u = __float_as_uint(f);
    u += 0x7fff + ((u >> 16) & 1);
    return (short)(u >> 16);
}
__device__ __forceinline__ float bf2f(unsigned short s) {
    return __uint_as_float(((unsigned)s) << 16);
}

__device__ __forceinline__ int load_idx(const void* ei, long long pos, int is64) {
    if (is64) return (int)((const long long*)ei)[pos];
    return ((const int*)ei)[pos];
}

// ================= CSR build via fixed-capacity bucket sort =================
// R16: per-edge random 4B store = 110MB write-amp. R17: 8192-bitonic = 150us.
// R18: counting-sort + per-node bitonic. R19: 1024-thread blocks wave-limited
// to 2/CU. R20: no hist pass (fixed regions), reg-cached finalize, half-wave
// sorts. Valid for N <= 131072 (17-bit src, 512 buckets). Here N = 100000.

#define TILE 4096
#define NBKT_MAX 512
#define CAP 12288      // per-bucket region; bucket cnt ~ Poisson(4350), 120 sigma

// fused: edge dtype detect + cursor zeroing (1 block)
__global__ __launch_bounds__(1024) void csr_init(
        const unsigned* __restrict__ ei, int* __restrict__ flag,
        int* __restrict__ gCursor) {
    int tid = threadIdx.x;
    if (tid < NBKT_MAX) gCursor[tid] = 0;
    if (tid == 0) {
        int ok = (ei[1] == 0u) & (ei[3] == 0u) & (ei[5] == 0u) &
                 (ei[7] == 0u) & (ei[9] == 0u) & (ei[11] == 0u);
        *flag = ok;
    }
}

// one-time: transpose weights to bf16 [col][k] so MFMA B-fragments are
// contiguous bf16x8 vector loads (was: 128 scalar loads + cvts PER THREAD).
__global__ __launch_bounds__(256) void prep_weights(
        const float* __restrict__ W0, const float* __restrict__ W1,
        const float* __restrict__ Wc,
        unsigned short* __restrict__ W0t, unsigned short* __restrict__ W1t,
        unsigned short* __restrict__ Wct) {
    int t = (int)(blockIdx.x * (size_t)blockDim.x + threadIdx.x);
    int stride = (int)(gridDim.x * (size_t)blockDim.x);
    for (int i = t; i < 64 * 128; i += stride) {           // W0t[col][k], K=128
        int col = i >> 7, k = i & 127;
        W0t[i] = (unsigned short)f2bf(W0[k * 64 + col]);
    }
    for (int i = t; i < 64 * 64; i += stride) {            // W1t[col][k], K=64
        int col = i >> 6, k = i & 63;
        W1t[i] = (unsigned short)f2bf(W1[k * 64 + col]);
    }
    for (int i = t; i < 48 * 64; i += stride) {            // Wct[col][k], K=64, pad 40..47
        int col = i >> 6, k = i & 63;
        Wct[i] = (col < 40) ? (unsigned short)f2bf(Wc[k * 40 + col]) : 0;
    }
}

// per-tile: LDS hist+scan+rank, stage packed (d_local<<17|s) by bucket,
// one cursor atomic per bucket per tile, coalesced run writes into the
// bucket's FIXED region packed[b*CAP ...].
__global__ __launch_bounds__(1024) void bucket_scatter(
        const void* __restrict__ ei, const int* __restrict__ flag,
        int* __restrict__ gCursor, unsigned* __restrict__ packed, int E, int N) {
    __shared__ int h[NBKT_MAX], excl[NBKT_MAX], bse[NBKT_MAX], cur[NBKT_MAX];
    __shared__ unsigned pck[TILE];
    __shared__ int tgt[TILE];
    int tid = threadIdx.x;
    int is64 = *flag;
    int total = E + N;
    int base = blockIdx.x * TILE;

    if (tid < NBKT_MAX) h[tid] = 0;
    __syncthreads();

    int s[4], d[4];
    bool ok[4];
#pragma unroll
    for (int j = 0; j < 4; j++) {
        int t = base + j * 1024 + tid;
        ok[j] = t < total;
        if (ok[j]) {
            if (t < E) { s[j] = load_idx(ei, t, is64); d[j] = load_idx(ei, (long long)E + t, is64); }
            else       { s[j] = d[j] = t - E; }
            atomicAdd(&h[d[j] >> 8], 1);
        }
    }
    __syncthreads();
    if (tid < NBKT_MAX) excl[tid] = h[tid];
    __syncthreads();
    for (int off = 1; off < NBKT_MAX; off <<= 1) {
        int v = (tid < NBKT_MAX && tid >= off) ? excl[tid - off] : 0;
        __syncthreads();
        if (tid < NBKT_MAX) excl[tid] += v;
        __syncthreads();
    }
    if (tid < NBKT_MAX) {
        excl[tid] -= h[tid];
        cur[tid] = excl[tid];
        bse[tid] = h[tid] ? atomicAdd(gCursor + tid, h[tid]) : 0;
    }
    __syncthreads();
#pragma unroll
    for (int j = 0; j < 4; j++) {
        if (ok[j]) {
            int b = d[j] >> 8;
            int ls = atomicAdd(&cur[b], 1);
            pck[ls] = ((unsigned)(d[j] & 255) << 17) | (unsigned)s[j];
            int off = bse[b] + (ls - excl[b]);
            tgt[ls] = (off < CAP) ? (b * CAP + off) : -1;   // overflow guard (never fires)
        }
    }
    __syncthreads();
    int nvalid = total - base; if (nvalid > TILE) nvalid = TILE;
    for (int i = tid; i < nvalid; i += 1024)
        if (tgt[i] >= 0) packed[tgt[i]] = pck[i];
}

// scan final bucket counts -> global bases for srcs/rowptr
__global__ __launch_bounds__(512) void bucket_scan(
        const int* __restrict__ gCursor, int* __restrict__ bucketStart) {
    __shared__ int sb[NBKT_MAX];
    int tid = threadIdx.x;
    int c = gCursor[tid];
    sb[tid] = c > CAP ? CAP : c;
    __syncthreads();
    for (int off = 1; off < NBKT_MAX; off <<= 1) {
        int v = (tid >= off) ? sb[tid - off] : 0;
        __syncthreads();
        sb[tid] += v;
        __syncthreads();
    }
    bucketStart[tid + 1] = sb[tid];
    if (tid == 0) bucketStart[0] = 0;
}

// per-bucket: reg-cache packed (ONE global pass), hist+scan -> rowptr, group
// into LDS, then canonical per-node sort: deg<=32 via 32-lane half-waves
// (15-step bitonic, 2 nodes/wave), 32<deg<=64 via 64-lane, >64 lane-0.
__global__ __launch_bounds__(1024) void bucket_finalize(
        const int* __restrict__ gCursor, const int* __restrict__ bucketStart,
        const unsigned* __restrict__ packed,
        int* __restrict__ rowptr, int* __restrict__ srcs, int N, int TOT) {
    __shared__ unsigned arr2[CAP];     // grouped by node (src only)
    __shared__ int cnt2[256], sc[256], cur[256];
    int tid = threadIdx.x;
    int b = blockIdx.x;
    int bs = bucketStart[b];
    int cnt = gCursor[b]; if (cnt > CAP) cnt = CAP;
    int nNodes = N - b * 256; if (nNodes > 256) nNodes = 256;

    if (tid < 256) cnt2[tid] = 0;
    __syncthreads();

    // single global read into registers (<=12/thread)
    unsigned pv[12];
#pragma unroll
    for (int i = 0; i < 12; i++) {
        int idx = i * 1024 + tid;
        if (idx < cnt) pv[i] = packed[(size_t)b * CAP + idx];
    }
#pragma unroll
    for (int i = 0; i < 12; i++) {
        int idx = i * 1024 + tid;
        if (idx < cnt) atomicAdd(&cnt2[pv[i] >> 17], 1);
    }
    __syncthreads();
    // inclusive scan of 256 counts
    if (tid < 256) sc[tid] = cnt2[tid];
    __syncthreads();
    for (int off = 1; off < 256; off <<= 1) {
        int v = (tid < 256 && tid >= off) ? sc[tid - off] : 0;
        __syncthreads();
        if (tid < 256) sc[tid] += v;
        __syncthreads();
    }
    if (tid < 256) cur[tid] = sc[tid] - cnt2[tid];     // exclusive start
    if (tid < nNodes) rowptr[b * 256 + tid] = bs + sc[tid] - cnt2[tid];
    if (b == 0 && tid == 0) rowptr[N] = TOT;
    __syncthreads();

    // group (order within segment racy; canonicalized by per-node sort)
#pragma unroll
    for (int i = 0; i < 12; i++) {
        int idx = i * 1024 + tid;
        if (idx < cnt) {
            int pos = atomicAdd(&cur[pv[i] >> 17], 1);
            arr2[pos] = pv[i] & 0x1FFFFu;
        }
    }
    __syncthreads();

    int wid = tid >> 6, lane = tid & 63;
    int half = lane >> 5, hl = lane & 31;
    // pass 1: deg<=32 nodes, 2 per wave (32-lane bitonic, 15 steps)
    for (int n2 = wid * 2; n2 < nNodes; n2 += 32) {
        int n = n2 + half;
        int deg = (n < nNodes) ? cnt2[n] : 0;
        if (deg >= 1 && deg <= 32) {
            int segs = sc[n] - deg;
            int v = (hl < deg) ? (int)arr2[segs + hl] : 0x7fffffff;
#pragma unroll
            for (int k = 2; k <= 32; k <<= 1) {
#pragma unroll
                for (int j = 16; j > 0; j >>= 1) {
                    if (j < k) {
                        int other = __shfl_xor(v, j);
                        bool dirDesc = (hl & k) != 0;
                        bool lower = (hl & j) == 0;
                        bool takeMin = (lower != dirDesc);
                        int mn = v < other ? v : other;
                        int mx = v < other ? other : v;
                        v = takeMin ? mn : mx;
                    }
                }
            }
            if (hl < deg) srcs[bs + segs + hl] = v;
        }
    }
    // pass 2: rare 32<deg<=64 (64-lane bitonic) and deg>64 (lane-0 insertion)
    for (int n = wid; n < nNodes; n += 16) {
        int deg = cnt2[n];
        if (deg <= 32) continue;
        int segs = sc[n] - deg;
        if (deg <= 64) {
            int v = (lane < deg) ? (int)arr2[segs + lane] : 0x7fffffff;
#pragma unroll
            for (int k = 2; k <= 64; k <<= 1) {
#pragma unroll
                for (int j = 32; j > 0; j >>= 1) {
                    if (j < k) {
                        int other = __shfl_xor(v, j);
                        bool dirDesc = (lane & k) != 0;
                        bool lower = (lane & j) == 0;
                        bool takeMin = (lower != dirDesc);
                        int mn = v < other ? v : other;
                        int mx = v < other ? other : v;
                        v = takeMin ? mn : mx;
                    }
                }
            }
            if (lane < deg) srcs[bs + segs + lane] = v;
        } else if (lane == 0) {
            for (int i = segs + 1; i < segs + deg; i++) {
                unsigned key = arr2[i];
                int j = i - 1;
                while (j >= segs && arr2[j] > key) { arr2[j + 1] = arr2[j]; j--; }
                arr2[j + 1] = key;
            }
            for (int i = 0; i < deg; i++) srcs[bs + segs + i] = (int)arr2[segs + i];
        }
    }
}

// ---------------- MFMA GEMM + attention scalars ----------------
// B-fragments from PRE-TRANSPOSED bf16 weights (Wt[col][k]) -> 16 vector loads.
// NO global-reduction atomics (R12 lesson: same-address atomicMax = ~155us drain).
template <int K, typename XT>
__global__ __launch_bounds__(256) void gemm_mfma(
        const XT* __restrict__ X, const unsigned short* __restrict__ Wt,
        const float* __restrict__ a_s, const float* __restrict__ a_d,
        unsigned short* __restrict__ Hbf,
        float* __restrict__ Sv, float* __restrict__ Dv, int N) {
    constexpr int KS = K / 32;
    int wid = threadIdx.x >> 6;
    int lane = threadIdx.x & 63;
    int base = blockIdx.x * 64 + wid * 16;
    if (base >= N) return;
    int l15 = lane & 15, lhi = lane >> 4;

    bf16x8 bfrag[KS][4];
#pragma unroll
    for (int ct = 0; ct < 4; ct++) {
        const unsigned short* wcol = Wt + (size_t)(ct * 16 + l15) * K + lhi * 8;
#pragma unroll
        for (int ks = 0; ks < KS; ks++)
            bfrag[ks][ct] = *(const bf16x8*)(wcol + ks * 32);
    }

    int row = base + l15; if (row >= N) row = N - 1;   // clamp; writes masked
    const XT* xr = X + (size_t)row * K + lhi * 8;
    bf16x8 afrag[KS];
#pragma unroll
    for (int ks = 0; ks < KS; ks++) {
        if constexpr (sizeof(XT) == 4) {
            float4 u0 = *(const float4*)(xr + ks * 32);
            float4 u1 = *(const float4*)(xr + ks * 32 + 4);
            afrag[ks][0] = f2bf(u0.x); afrag[ks][1] = f2bf(u0.y);
            afrag[ks][2] = f2bf(u0.z); afrag[ks][3] = f2bf(u0.w);
            afrag[ks][4] = f2bf(u1.x); afrag[ks][5] = f2bf(u1.y);
            afrag[ks][6] = f2bf(u1.z); afrag[ks][7] = f2bf(u1.w);
        } else {
            afrag[ks] = *(const bf16x8*)(xr + ks * 32);
        }
    }

    f32x4 acc[4] = {{0.f,0.f,0.f,0.f},{0.f,0.f,0.f,0.f},{0.f,0.f,0.f,0.f},{0.f,0.f,0.f,0.f}};
#pragma unroll
    for (int ks = 0; ks < KS; ks++)
#pragma unroll
        for (int ct = 0; ct < 4; ct++)
            acc[ct] = __builtin_amdgcn_mfma_f32_16x16x32_bf16(afrag[ks], bfrag[ks][ct], acc[ct], 0, 0, 0);

    float asv[4], adv[4];
#pragma unroll
    for (int ct = 0; ct < 4; ct++) { asv[ct] = a_s[ct * 16 + l15]; adv[ct] = a_d[ct * 16 + l15]; }

#pragma unroll
    for (int r = 0; r < 4; r++) {
        int grow = base + lhi * 4 + r;
        bool ok = grow < N;
        float sv = 0.f, dv = 0.f;
#pragma unroll
        for (int ct = 0; ct < 4; ct++) {
            float v = acc[ct][r];
            if (ok) Hbf[(size_t)grow * 64 + ct * 16 + l15] = (unsigned short)f2bf(v);
            sv = fmaf(v, asv[ct], sv);
            dv = fmaf(v, adv[ct], dv);
        }
#pragma unroll
        for (int off = 1; off < 16; off <<= 1) {
            sv += __shfl_xor(sv, off);
            dv += __shfl_xor(dv, off);
        }
        if (ok && l15 == 0) { Sv[grow] = sv; Dv[grow] = dv; }
    }
}

// ---------------- quarter-wave aggregation, p inline, srcs prefetch ----------------
// 16 lanes per node, lane ql owns channels 4ql..4ql+3 (8B H-slice).
// srcs for group j+4 are loaded during group j's compute -> the per-iteration
// chain is only {Sv,H}->fma (load reorder only; fp math order IDENTICAL to R20).
// Deterministic given canonically-sorted srcs. M=0 shift (exact ratios, |e|<~10).
__global__ __launch_bounds__(256) void gat_agg_q(
        const int* __restrict__ rowptr, const int* __restrict__ srcs,
        const unsigned short* __restrict__ H, const float* __restrict__ Sv,
        const float* __restrict__ Dv, const float* __restrict__ b,
        unsigned short* __restrict__ OutRow, int N) {
    int wv = (int)((blockIdx.x * (size_t)blockDim.x + threadIdx.x) >> 6);
    int lane = threadIdx.x & 63;
    int q = lane >> 4, ql = lane & 15;
    int node = wv * 4 + q;
    if (node >= N) return;
    int start = rowptr[node];
    int deg = rowptr[node + 1] - start;
    float dvv = Dv[node];

    const uint2* Hd = (const uint2*)H;            // 8B units: row = 16 x uint2
    float a0 = 0.f, a1 = 0.f, a2 = 0.f, a3 = 0.f, den = 0.f;

    int sN0 = 0, sN1 = 0, sN2 = 0, sN3 = 0;
    if (deg >= 4) {
        sN0 = srcs[start];     sN1 = srcs[start + 1];
        sN2 = srcs[start + 2]; sN3 = srcs[start + 3];
    }
    int j = 0;
    for (; j + 4 <= deg; j += 4) {
        int s0 = sN0, s1 = sN1, s2 = sN2, s3 = sN3;
        if (j + 8 <= deg) {                        // prefetch next group
            sN0 = srcs[start + j + 4]; sN1 = srcs[start + j + 5];
            sN2 = srcs[start + j + 6]; sN3 = srcs[start + j + 7];
        }
        float e0 = Sv[s0] + dvv, e1 = Sv[s1] + dvv,
              e2 = Sv[s2] + dvv, e3 = Sv[s3] + dvv;
        uint2 h0 = Hd[(size_t)s0 * 16 + ql];
        uint2 h1 = Hd[(size_t)s1 * 16 + ql];
        uint2 h2 = Hd[(size_t)s2 * 16 + ql];
        uint2 h3 = Hd[(size_t)s3 * 16 + ql];
        e0 = (e0 > 0.f) ? e0 : 0.2f * e0;
        e1 = (e1 > 0.f) ? e1 : 0.2f * e1;
        e2 = (e2 > 0.f) ? e2 : 0.2f * e2;
        e3 = (e3 > 0.f) ? e3 : 0.2f * e3;
        float p0 = __expf(e0), p1 = __expf(e1), p2 = __expf(e2), p3 = __expf(e3);
        den += (p0 + p1) + (p2 + p3);
        a0 = fmaf(p0, __uint_as_float(h0.x << 16), a0);
        a1 = fmaf(p0, __uint_as_float(h0.x & 0xffff0000u), a1);
        a2 = fmaf(p0, __uint_as_float(h0.y << 16), a2);
        a3 = fmaf(p0, __uint_as_float(h0.y & 0xffff0000u), a3);
        a0 = fmaf(p1, __uint_as_float(h1.x << 16), a0);
        a1 = fmaf(p1, __uint_as_float(h1.x & 0xffff0000u), a1);
        a2 = fmaf(p1, __uint_as_float(h1.y << 16), a2);
        a3 = fmaf(p1, __uint_as_float(h1.y & 0xffff0000u), a3);
        a0 = fmaf(p2, __uint_as_float(h2.x << 16), a0);
        a1 = fmaf(p2, __uint_as_float(h2.x & 0xffff0000u), a1);
        a2 = fmaf(p2, __uint_as_float(h2.y << 16), a2);
        a3 = fmaf(p2, __uint_as_float(h2.y & 0xffff0000u), a3);
        a0 = fmaf(p3, __uint_as_float(h3.x << 16), a0);
        a1 = fmaf(p3, __uint_as_float(h3.x & 0xffff0000u), a1);
        a2 = fmaf(p3, __uint_as_float(h3.y << 16), a2);
        a3 = fmaf(p3, __uint_as_float(h3.y & 0xffff0000u), a3);
    }
    for (; j < deg; j++) {
        int s0 = srcs[start + j];
        float e0 = Sv[s0] + dvv;
        uint2 h0 = Hd[(size_t)s0 * 16 + ql];
        e0 = (e0 > 0.f) ? e0 : 0.2f * e0;
        float p0 = __expf(e0);
        den += p0;
        a0 = fmaf(p0, __uint_as_float(h0.x << 16), a0);
        a1 = fmaf(p0, __uint_as_float(h0.x & 0xffff0000u), a1);
        a2 = fmaf(p0, __uint_as_float(h0.y << 16), a2);
        a3 = fmaf(p0, __uint_as_float(h0.y & 0xffff0000u), a3);
    }

    float rden = 1.0f / (den + 1e-16f);
    float4 bb = *(const float4*)(b + ql * 4);
    float v0 = fmaf(a0, rden, bb.x); v0 = v0 > 0.f ? v0 : 0.f;
    float v1 = fmaf(a1, rden, bb.y); v1 = v1 > 0.f ? v1 : 0.f;
    float v2 = fmaf(a2, rden, bb.z); v2 = v2 > 0.f ? v2 : 0.f;
    float v3 = fmaf(a3, rden, bb.w); v3 = v3 > 0.f ? v3 : 0.f;
    uint2 pack;
    pack.x = ((unsigned)(unsigned short)f2bf(v1) << 16) | (unsigned short)f2bf(v0);
    pack.y = ((unsigned)(unsigned short)f2bf(v3) << 16) | (unsigned short)f2bf(v2);
    *(uint2*)(OutRow + (size_t)node * 64 + ql * 4) = pack;
}

// ---------------- classifier via MFMA (pre-transposed bf16 Wct[48][64]) ----------------
__global__ __launch_bounds__(256) void classifier_mfma(
        const unsigned short* __restrict__ H, const unsigned short* __restrict__ Wct,
        const float* __restrict__ bc, float* __restrict__ out, int N) {
    int wid = threadIdx.x >> 6;
    int lane = threadIdx.x & 63;
    int base = blockIdx.x * 64 + wid * 16;
    if (base >= N) return;
    int l15 = lane & 15, lhi = lane >> 4;
    int colv[3]; bool cok[3];
#pragma unroll
    for (int ct = 0; ct < 3; ct++) { colv[ct] = ct * 16 + l15; cok[ct] = colv[ct] < 40; }

    bf16x8 bfrag[2][3];
#pragma unroll
    for (int ct = 0; ct < 3; ct++) {
        const unsigned short* wcol = Wct + (size_t)colv[ct] * 64 + lhi * 8;
#pragma unroll
        for (int ks = 0; ks < 2; ks++)
            bfrag[ks][ct] = *(const bf16x8*)(wcol + ks * 32);
    }

    int row = base + l15; if (row >= N) row = N - 1;   // clamp; writes masked
    const unsigned short* xr = H + (size_t)row * 64 + lhi * 8;
    bf16x8 afrag[2] = { *(const bf16x8*)xr, *(const bf16x8*)(xr + 32) };

    f32x4 acc[3] = {{0.f,0.f,0.f,0.f},{0.f,0.f,0.f,0.f},{0.f,0.f,0.f,0.f}};
#pragma unroll
    for (int ks = 0; ks < 2; ks++)
#pragma unroll
        for (int ct = 0; ct < 3; ct++)
            acc[ct] = __builtin_amdgcn_mfma_f32_16x16x32_bf16(afrag[ks], bfrag[ks][ct], acc[ct], 0, 0, 0);

    float bcv[3];
#pragma unroll
    for (int ct = 0; ct < 3; ct++) bcv[ct] = cok[ct] ? bc[colv[ct]] : 0.f;

#pragma unroll
    for (int r = 0; r < 4; r++) {
        int node = base + lhi * 4 + r;
        bool ok = node < N;
        float lg[3];
#pragma unroll
        for (int ct = 0; ct < 3; ct++)
            lg[ct] = cok[ct] ? (acc[ct][r] + bcv[ct]) : -INFINITY;
        float m = fmaxf(fmaxf(lg[0], lg[1]), lg[2]);
#pragma unroll
        for (int off = 1; off < 16; off <<= 1) m = fmaxf(m, __shfl_xor(m, off));
        float ex = 0.f;
#pragma unroll
        for (int ct = 0; ct < 3; ct++) ex += cok[ct] ? __expf(lg[ct] - m) : 0.f;
#pragma unroll
        for (int off = 1; off < 16; off <<= 1) ex += __shfl_xor(ex, off);
        float ls = __logf(ex);
        if (ok) {
#pragma unroll
            for (int ct = 0; ct < 3; ct++)
                if (cok[ct]) out[(size_t)node * 40 + colv[ct]] = lg[ct] - m - ls;
        }
    }
}

// ---------------- launch ----------------

extern "C" void kernel_launch(void* const* d_in, const int* in_sizes, int n_in,
                              void* d_out, int out_size, void* d_ws, size_t ws_size,
                              hipStream_t stream) {
    const float* x   = (const float*)d_in[0];
    const void*  ei  = d_in[1];
    const float* W0  = (const float*)d_in[2];
    const float* as0 = (const float*)d_in[3];
    const float* ad0 = (const float*)d_in[4];
    const float* b0  = (const float*)d_in[5];
    const float* W1  = (const float*)d_in[6];
    const float* as1 = (const float*)d_in[7];
    const float* ad1 = (const float*)d_in[8];
    const float* b1  = (const float*)d_in[9];
    const float* Wc  = (const float*)d_in[10];
    const float* bc  = (const float*)d_in[11];
    float* out = (float*)d_out;

    const int N = in_sizes[0] / 128;   // 100000
    const int E = in_sizes[1] / 2;     // 1600000
    const int TOT = E + N;             // with self loops
    const int nbkt = (N + 255) / 256;  // dst buckets

    char* w = (char*)d_ws;
    unsigned short* HAbf    = (unsigned short*)w; w += (size_t)N * 64 * 2;  // gemm out (bf16)
    unsigned short* HCbf    = (unsigned short*)w; w += (size_t)N * 64 * 2;  // agg out (bf16)
    float*          Sv      = (float*)w;          w += (size_t)N * 4;
    float*          Dv      = (float*)w;          w += (size_t)N * 4;
    int*            rowptr  = (int*)w;            w += (size_t)(N + 1) * 4;
    int*            srcs    = (int*)w;            w += (size_t)TOT * 4;
    unsigned*       packed  = (unsigned*)w;       w += (size_t)nbkt * CAP * 4;  // fixed regions
    int*            gCursor = (int*)w;            w += NBKT_MAX * 4;
    int*            bktStart= (int*)w;            w += (NBKT_MAX + 1) * 4;
    int*            flag    = (int*)w;            w += 256;
    unsigned short* W0t     = (unsigned short*)w; w += 64 * 128 * 2;
    unsigned short* W1t     = (unsigned short*)w; w += 64 * 64 * 2;
    unsigned short* Wct     = (unsigned short*)w; w += 48 * 64 * 2;

    const int B = 256;
    const int gQuad  = (N + 15) / 16;            // agg: 4 nodes/wave x 4 waves/block
    const int gTile  = (N + 63) / 64;            // mfma: 64 rows per block
    const int nTileE = (TOT + TILE - 1) / TILE;  // edge tiles (4096)

    // ---- prep + CSR build (once; reused by both layers) ----
    csr_init<<<1, 1024, 0, stream>>>((const unsigned*)ei, flag, gCursor);
    prep_weights<<<8, B, 0, stream>>>(W0, W1, Wc, W0t, W1t, Wct);
    bucket_scatter<<<nTileE, 1024, 0, stream>>>(ei, flag, gCursor, packed, E, N);
    bucket_scan<<<1, NBKT_MAX, 0, stream>>>(gCursor, bktStart);
    bucket_finalize<<<nbkt, 1024, 0, stream>>>(gCursor, bktStart, packed, rowptr, srcs, N, TOT);

    // ---- layer 0 ----
    gemm_mfma<128, float><<<gTile, B, 0, stream>>>(x, W0t, as0, ad0, HAbf, Sv, Dv, N);
    gat_agg_q<<<gQuad, B, 0, stream>>>(rowptr, srcs, HAbf, Sv, Dv, b0, HCbf, N);

    // ---- layer 1 ----
    gemm_mfma<64, unsigned short><<<gTile, B, 0, stream>>>(HCbf, W1t, as1, ad1, HAbf, Sv, Dv, N);
    gat_agg_q<<<gQuad, B, 0, stream>>>(rowptr, srcs, HAbf, Sv, Dv, b1, HCbf, N);

    // ---- classifier + log_softmax (MFMA) ----
    classifier_mfma<<<gTile, B, 0, stream>>>(HCbf, Wct, bc, out, N);
}

// Round 22
// 177.059 us; speedup vs baseline: 1.0133x; 1.0133x over previous
//
#include <hip/hip_runtime.h>
#include <hip/hip_bf16.h>
#include <math.h>

typedef __attribute__((ext_vector_type(8))) short bf16x8;
typedef __attribute__((ext_vector_type(4))) float f32x4;

// ---------------- helpers ----------------

__device__ __forceinline__ short f2bf(float f) {           // RNE fp32->bf16
    unsigned u = __float_as_uint(f);
    u += 0x7fff + ((u >> 16) & 1);
    return (short)(u >> 16);
}
__device__ __forceinline__ float bf2f(unsigned short s) {
    return __uint_as_float(((unsigned)s) << 16);
}

__device__ __forceinline__ int load_idx(const void* ei, long long pos, int is64) {
    if (is64) return (int)((const long long*)ei)[pos];
    return ((const int*)ei)[pos];
}

// ================= CSR build via fixed-capacity bucket sort =================
// R16: random 4B stores = 110MB write-amp. R17: 8192-bitonic = 150us. R18/R20:
// counting-sort + per-node bitonic, reg-cached, no hist pass. R22: 128-node
// buckets + 512-thread finalize (4 blocks/CU, all ~780 blocks resident, half
// the per-block critical path); per-block bucketStart reduce (scan kernel gone).
// Valid for N <= 131072 (17-bit src, 1024 buckets). Here N = 100000.

#define TILE 4096
#define NBKT_MAX 1024
#define BKT_SH 7       // 128 nodes per bucket
#define CAP 6912       // per-bucket region; cnt ~ Poisson(2175), ~100 sigma

// fused one-time prep: cursor zeroing + dtype detect + weight transpose (bf16)
__global__ __launch_bounds__(256) void prep_init(
        const unsigned* __restrict__ ei, int* __restrict__ flag,
        int* __restrict__ gCursor,
        const float* __restrict__ W0, const float* __restrict__ W1,
        const float* __restrict__ Wc,
        unsigned short* __restrict__ W0t, unsigned short* __restrict__ W1t,
        unsigned short* __restrict__ Wct) {
    int t = (int)(blockIdx.x * (size_t)blockDim.x + threadIdx.x);
    int stride = (int)(gridDim.x * (size_t)blockDim.x);
    for (int i = t; i < NBKT_MAX; i += stride) gCursor[i] = 0;
    if (t == 0) {
        int ok = (ei[1] == 0u) & (ei[3] == 0u) & (ei[5] == 0u) &
                 (ei[7] == 0u) & (ei[9] == 0u) & (ei[11] == 0u);
        *flag = ok;
    }
    for (int i = t; i < 64 * 128; i += stride) {           // W0t[col][k], K=128
        int col = i >> 7, k = i & 127;
        W0t[i] = (unsigned short)f2bf(W0[k * 64 + col]);
    }
    for (int i = t; i < 64 * 64; i += stride) {            // W1t[col][k], K=64
        int col = i >> 6, k = i & 63;
        W1t[i] = (unsigned short)f2bf(W1[k * 64 + col]);
    }
    for (int i = t; i < 48 * 64; i += stride) {            // Wct[col][k], pad 40..47
        int col = i >> 6, k = i & 63;
        Wct[i] = (col < 40) ? (unsigned short)f2bf(Wc[k * 40 + col]) : 0;
    }
}

// per-tile: LDS hist+scan+rank, stage packed (d_local<<17|s) by bucket,
// one cursor atomic per bucket per tile, coalesced run writes into the
// bucket's FIXED region packed[b*CAP ...].
__global__ __launch_bounds__(1024) void bucket_scatter(
        const void* __restrict__ ei, const int* __restrict__ flag,
        int* __restrict__ gCursor, unsigned* __restrict__ packed, int E, int N) {
    __shared__ int h[NBKT_MAX], excl[NBKT_MAX], bse[NBKT_MAX], cur[NBKT_MAX];
    __shared__ unsigned pck[TILE];
    __shared__ int tgt[TILE];
    int tid = threadIdx.x;
    int is64 = *flag;
    int total = E + N;
    int base = blockIdx.x * TILE;

    h[tid] = 0;                     // NBKT_MAX == blockDim.x == 1024
    __syncthreads();

    int s[4], d[4];
    bool ok[4];
#pragma unroll
    for (int j = 0; j < 4; j++) {
        int t = base + j * 1024 + tid;
        ok[j] = t < total;
        if (ok[j]) {
            if (t < E) { s[j] = load_idx(ei, t, is64); d[j] = load_idx(ei, (long long)E + t, is64); }
            else       { s[j] = d[j] = t - E; }
            atomicAdd(&h[d[j] >> BKT_SH], 1);
        }
    }
    __syncthreads();
    excl[tid] = h[tid];
    __syncthreads();
    for (int off = 1; off < NBKT_MAX; off <<= 1) {
        int v = (tid >= off) ? excl[tid - off] : 0;
        __syncthreads();
        excl[tid] += v;
        __syncthreads();
    }
    excl[tid] -= h[tid];
    cur[tid] = excl[tid];
    bse[tid] = h[tid] ? atomicAdd(gCursor + tid, h[tid]) : 0;
    __syncthreads();
#pragma unroll
    for (int j = 0; j < 4; j++) {
        if (ok[j]) {
            int b = d[j] >> BKT_SH;
            int ls = atomicAdd(&cur[b], 1);
            pck[ls] = ((unsigned)(d[j] & 127) << 17) | (unsigned)s[j];
            int off = bse[b] + (ls - excl[b]);
            tgt[ls] = (off < CAP) ? (b * CAP + off) : -1;   // overflow guard (never fires)
        }
    }
    __syncthreads();
    int nvalid = total - base; if (nvalid > TILE) nvalid = TILE;
    for (int i = tid; i < nvalid; i += 1024)
        if (tgt[i] >= 0) packed[tgt[i]] = pck[i];
}

// per-bucket (512 threads, 4 blocks/CU): own bucketStart reduce; reg-cache
// packed (ONE global pass), hist+scan -> rowptr, group into LDS, canonical
// per-node sort (deg<=32: 32-lane half-waves; <=64: 64-lane; >64: lane-0).
__global__ __launch_bounds__(512) void bucket_finalize(
        const int* __restrict__ gCursor, const unsigned* __restrict__ packed,
        int* __restrict__ rowptr, int* __restrict__ srcs, int N, int TOT) {
    __shared__ unsigned arr2[CAP];     // grouped by node (src only)
    __shared__ int cnt2[128], sc[128], cur[128];
    __shared__ int red[512];
    int tid = threadIdx.x;
    int b = blockIdx.x;

    // bucketStart[b] = sum_{i<b} min(gCursor[i], CAP)
    int accs = 0;
    for (int i = tid; i < b; i += 512) {
        int c = gCursor[i];
        accs += (c > CAP ? CAP : c);
    }
    red[tid] = accs;
    __syncthreads();
    for (int off = 256; off > 0; off >>= 1) {
        if (tid < off) red[tid] += red[tid + off];
        __syncthreads();
    }
    int bs = red[0];
    int cnt = gCursor[b]; if (cnt > CAP) cnt = CAP;
    int nNodes = N - (b << BKT_SH); if (nNodes > 128) nNodes = 128;

    if (tid < 128) cnt2[tid] = 0;
    __syncthreads();

    // single global read into registers (<=14/thread)
    unsigned pv[14];
#pragma unroll
    for (int i = 0; i < 14; i++) {
        int idx = i * 512 + tid;
        if (idx < cnt) pv[i] = packed[(size_t)b * CAP + idx];
    }
#pragma unroll
    for (int i = 0; i < 14; i++) {
        int idx = i * 512 + tid;
        if (idx < cnt) atomicAdd(&cnt2[pv[i] >> 17], 1);
    }
    __syncthreads();
    // inclusive scan of 128 counts
    if (tid < 128) sc[tid] = cnt2[tid];
    __syncthreads();
    for (int off = 1; off < 128; off <<= 1) {
        int v = (tid < 128 && tid >= off) ? sc[tid - off] : 0;
        __syncthreads();
        if (tid < 128) sc[tid] += v;
        __syncthreads();
    }
    if (tid < 128) cur[tid] = sc[tid] - cnt2[tid];     // exclusive start
    if (tid < nNodes) rowptr[(b << BKT_SH) + tid] = bs + sc[tid] - cnt2[tid];
    if (b == 0 && tid == 0) rowptr[N] = TOT;
    __syncthreads();

    // group (order within segment racy; canonicalized by per-node sort)
#pragma unroll
    for (int i = 0; i < 14; i++) {
        int idx = i * 512 + tid;
        if (idx < cnt) {
            int pos = atomicAdd(&cur[pv[i] >> 17], 1);
            arr2[pos] = pv[i] & 0x1FFFFu;
        }
    }
    __syncthreads();

    int wid = tid >> 6, lane = tid & 63;               // 8 waves
    int half = lane >> 5, hl = lane & 31;
    // pass 1: deg<=32 nodes, 2 per wave (32-lane bitonic, 15 steps)
    for (int n2 = wid * 2; n2 < nNodes; n2 += 16) {
        int n = n2 + half;
        int deg = (n < nNodes) ? cnt2[n] : 0;
        if (deg >= 1 && deg <= 32) {
            int segs = sc[n] - deg;
            int v = (hl < deg) ? (int)arr2[segs + hl] : 0x7fffffff;
#pragma unroll
            for (int k = 2; k <= 32; k <<= 1) {
#pragma unroll
                for (int j = 16; j > 0; j >>= 1) {
                    if (j < k) {
                        int other = __shfl_xor(v, j);
                        bool dirDesc = (hl & k) != 0;
                        bool lower = (hl & j) == 0;
                        bool takeMin = (lower != dirDesc);
                        int mn = v < other ? v : other;
                        int mx = v < other ? other : v;
                        v = takeMin ? mn : mx;
                    }
                }
            }
            if (hl < deg) srcs[bs + segs + hl] = v;
        }
    }
    // pass 2: rare 32<deg<=64 (64-lane bitonic) and deg>64 (lane-0 insertion)
    for (int n = wid; n < nNodes; n += 8) {
        int deg = cnt2[n];
        if (deg <= 32) continue;
        int segs = sc[n] - deg;
        if (deg <= 64) {
            int v = (lane < deg) ? (int)arr2[segs + lane] : 0x7fffffff;
#pragma unroll
            for (int k = 2; k <= 64; k <<= 1) {
#pragma unroll
                for (int j = 32; j > 0; j >>= 1) {
                    if (j < k) {
                        int other = __shfl_xor(v, j);
                        bool dirDesc = (lane & k) != 0;
                        bool lower = (lane & j) == 0;
                        bool takeMin = (lower != dirDesc);
                        int mn = v < other ? v : other;
                        int mx = v < other ? other : v;
                        v = takeMin ? mn : mx;
                    }
                }
            }
            if (lane < deg) srcs[bs + segs + lane] = v;
        } else if (lane == 0) {
            for (int i = segs + 1; i < segs + deg; i++) {
                unsigned key = arr2[i];
                int j = i - 1;
                while (j >= segs && arr2[j] > key) { arr2[j + 1] = arr2[j]; j--; }
                arr2[j + 1] = key;
            }
            for (int i = 0; i < deg; i++) srcs[bs + segs + i] = (int)arr2[segs + i];
        }
    }
}

// ---------------- MFMA GEMM + attention scalars ----------------
// B-fragments from pre-transposed bf16 weights (Wt[col][k]).
// NO global-reduction atomics (R12 lesson: same-address atomicMax = ~155us drain).
template <int K, typename XT>
__global__ __launch_bounds__(256) void gemm_mfma(
        const XT* __restrict__ X, const unsigned short* __restrict__ Wt,
        const float* __restrict__ a_s, const float* __restrict__ a_d,
        unsigned short* __restrict__ Hbf,
        float* __restrict__ Sv, float* __restrict__ Dv, int N) {
    constexpr int KS = K / 32;
    int wid = threadIdx.x >> 6;
    int lane = threadIdx.x & 63;
    int base = blockIdx.x * 64 + wid * 16;
    if (base >= N) return;
    int l15 = lane & 15, lhi = lane >> 4;

    bf16x8 bfrag[KS][4];
#pragma unroll
    for (int ct = 0; ct < 4; ct++) {
        const unsigned short* wcol = Wt + (size_t)(ct * 16 + l15) * K + lhi * 8;
#pragma unroll
        for (int ks = 0; ks < KS; ks++)
            bfrag[ks][ct] = *(const bf16x8*)(wcol + ks * 32);
    }

    int row = base + l15; if (row >= N) row = N - 1;   // clamp; writes masked
    const XT* xr = X + (size_t)row * K + lhi * 8;
    bf16x8 afrag[KS];
#pragma unroll
    for (int ks = 0; ks < KS; ks++) {
        if constexpr (sizeof(XT) == 4) {
            float4 u0 = *(const float4*)(xr + ks * 32);
            float4 u1 = *(const float4*)(xr + ks * 32 + 4);
            afrag[ks][0] = f2bf(u0.x); afrag[ks][1] = f2bf(u0.y);
            afrag[ks][2] = f2bf(u0.z); afrag[ks][3] = f2bf(u0.w);
            afrag[ks][4] = f2bf(u1.x); afrag[ks][5] = f2bf(u1.y);
            afrag[ks][6] = f2bf(u1.z); afrag[ks][7] = f2bf(u1.w);
        } else {
            afrag[ks] = *(const bf16x8*)(xr + ks * 32);
        }
    }

    f32x4 acc[4] = {{0.f,0.f,0.f,0.f},{0.f,0.f,0.f,0.f},{0.f,0.f,0.f,0.f},{0.f,0.f,0.f,0.f}};
#pragma unroll
    for (int ks = 0; ks < KS; ks++)
#pragma unroll
        for (int ct = 0; ct < 4; ct++)
            acc[ct] = __builtin_amdgcn_mfma_f32_16x16x32_bf16(afrag[ks], bfrag[ks][ct], acc[ct], 0, 0, 0);

    float asv[4], adv[4];
#pragma unroll
    for (int ct = 0; ct < 4; ct++) { asv[ct] = a_s[ct * 16 + l15]; adv[ct] = a_d[ct * 16 + l15]; }

#pragma unroll
    for (int r = 0; r < 4; r++) {
        int grow = base + lhi * 4 + r;
        bool ok = grow < N;
        float sv = 0.f, dv = 0.f;
#pragma unroll
        for (int ct = 0; ct < 4; ct++) {
            float v = acc[ct][r];
            if (ok) Hbf[(size_t)grow * 64 + ct * 16 + l15] = (unsigned short)f2bf(v);
            sv = fmaf(v, asv[ct], sv);
            dv = fmaf(v, adv[ct], dv);
        }
#pragma unroll
        for (int off = 1; off < 16; off <<= 1) {
            sv += __shfl_xor(sv, off);
            dv += __shfl_xor(dv, off);
        }
        if (ok && l15 == 0) { Sv[grow] = sv; Dv[grow] = dv; }
    }
}

// ---------------- quarter-wave aggregation, p computed inline (R20 form) ----------------
// 16 lanes per node, lane ql owns channels 4ql..4ql+3 (8B H-slice). Deterministic
// given canonically-sorted srcs. M=0 shift (exact ratios, |e|<~10).
__global__ __launch_bounds__(256) void gat_agg_q(
        const int* __restrict__ rowptr, const int* __restrict__ srcs,
        const unsigned short* __restrict__ H, const float* __restrict__ Sv,
        const float* __restrict__ Dv, const float* __restrict__ b,
        unsigned short* __restrict__ OutRow, int N) {
    int wv = (int)((blockIdx.x * (size_t)blockDim.x + threadIdx.x) >> 6);
    int lane = threadIdx.x & 63;
    int q = lane >> 4, ql = lane & 15;
    int node = wv * 4 + q;
    if (node >= N) return;
    int start = rowptr[node];
    int deg = rowptr[node + 1] - start;
    float dvv = Dv[node];

    const uint2* Hd = (const uint2*)H;            // 8B units: row = 16 x uint2
    float a0 = 0.f, a1 = 0.f, a2 = 0.f, a3 = 0.f, den = 0.f;

    int j = 0;
    for (; j + 4 <= deg; j += 4) {
        int s0 = srcs[start + j], s1 = srcs[start + j + 1],
            s2 = srcs[start + j + 2], s3 = srcs[start + j + 3];
        float e0 = Sv[s0] + dvv, e1 = Sv[s1] + dvv,
              e2 = Sv[s2] + dvv, e3 = Sv[s3] + dvv;
        uint2 h0 = Hd[(size_t)s0 * 16 + ql];
        uint2 h1 = Hd[(size_t)s1 * 16 + ql];
        uint2 h2 = Hd[(size_t)s2 * 16 + ql];
        uint2 h3 = Hd[(size_t)s3 * 16 + ql];
        e0 = (e0 > 0.f) ? e0 : 0.2f * e0;
        e1 = (e1 > 0.f) ? e1 : 0.2f * e1;
        e2 = (e2 > 0.f) ? e2 : 0.2f * e2;
        e3 = (e3 > 0.f) ? e3 : 0.2f * e3;
        float p0 = __expf(e0), p1 = __expf(e1), p2 = __expf(e2), p3 = __expf(e3);
        den += (p0 + p1) + (p2 + p3);
        a0 = fmaf(p0, __uint_as_float(h0.x << 16), a0);
        a1 = fmaf(p0, __uint_as_float(h0.x & 0xffff0000u), a1);
        a2 = fmaf(p0, __uint_as_float(h0.y << 16), a2);
        a3 = fmaf(p0, __uint_as_float(h0.y & 0xffff0000u), a3);
        a0 = fmaf(p1, __uint_as_float(h1.x << 16), a0);
        a1 = fmaf(p1, __uint_as_float(h1.x & 0xffff0000u), a1);
        a2 = fmaf(p1, __uint_as_float(h1.y << 16), a2);
        a3 = fmaf(p1, __uint_as_float(h1.y & 0xffff0000u), a3);
        a0 = fmaf(p2, __uint_as_float(h2.x << 16), a0);
        a1 = fmaf(p2, __uint_as_float(h2.x & 0xffff0000u), a1);
        a2 = fmaf(p2, __uint_as_float(h2.y << 16), a2);
        a3 = fmaf(p2, __uint_as_float(h2.y & 0xffff0000u), a3);
        a0 = fmaf(p3, __uint_as_float(h3.x << 16), a0);
        a1 = fmaf(p3, __uint_as_float(h3.x & 0xffff0000u), a1);
        a2 = fmaf(p3, __uint_as_float(h3.y << 16), a2);
        a3 = fmaf(p3, __uint_as_float(h3.y & 0xffff0000u), a3);
    }
    for (; j < deg; j++) {
        int s0 = srcs[start + j];
        float e0 = Sv[s0] + dvv;
        uint2 h0 = Hd[(size_t)s0 * 16 + ql];
        e0 = (e0 > 0.f) ? e0 : 0.2f * e0;
        float p0 = __expf(e0);
        den += p0;
        a0 = fmaf(p0, __uint_as_float(h0.x << 16), a0);
        a1 = fmaf(p0, __uint_as_float(h0.x & 0xffff0000u), a1);
        a2 = fmaf(p0, __uint_as_float(h0.y << 16), a2);
        a3 = fmaf(p0, __uint_as_float(h0.y & 0xffff0000u), a3);
    }

    float rden = 1.0f / (den + 1e-16f);
    float4 bb = *(const float4*)(b + ql * 4);
    float v0 = fmaf(a0, rden, bb.x); v0 = v0 > 0.f ? v0 : 0.f;
    float v1 = fmaf(a1, rden, bb.y); v1 = v1 > 0.f ? v1 : 0.f;
    float v2 = fmaf(a2, rden, bb.z); v2 = v2 > 0.f ? v2 : 0.f;
    float v3 = fmaf(a3, rden, bb.w); v3 = v3 > 0.f ? v3 : 0.f;
    uint2 pack;
    pack.x = ((unsigned)(unsigned short)f2bf(v1) << 16) | (unsigned short)f2bf(v0);
    pack.y = ((unsigned)(unsigned short)f2bf(v3) << 16) | (unsigned short)f2bf(v2);
    *(uint2*)(OutRow + (size_t)node * 64 + ql * 4) = pack;
}

// ---------------- classifier via MFMA (pre-transposed bf16 Wct[48][64]) ----------------
__global__ __launch_bounds__(256) void classifier_mfma(
        const unsigned short* __restrict__ H, const unsigned short* __restrict__ Wct,
        const float* __restrict__ bc, float* __restrict__ out, int N) {
    int wid = threadIdx.x >> 6;
    int lane = threadIdx.x & 63;
    int base = blockIdx.x * 64 + wid * 16;
    if (base >= N) return;
    int l15 = lane & 15, lhi = lane >> 4;
    int colv[3]; bool cok[3];
#pragma unroll
    for (int ct = 0; ct < 3; ct++) { colv[ct] = ct * 16 + l15; cok[ct] = colv[ct] < 40; }

    bf16x8 bfrag[2][3];
#pragma unroll
    for (int ct = 0; ct < 3; ct++) {
        const unsigned short* wcol = Wct + (size_t)colv[ct] * 64 + lhi * 8;
#pragma unroll
        for (int ks = 0; ks < 2; ks++)
            bfrag[ks][ct] = *(const bf16x8*)(wcol + ks * 32);
    }

    int row = base + l15; if (row >= N) row = N - 1;   // clamp; writes masked
    const unsigned short* xr = H + (size_t)row * 64 + lhi * 8;
    bf16x8 afrag[2] = { *(const bf16x8*)xr, *(const bf16x8*)(xr + 32) };

    f32x4 acc[3] = {{0.f,0.f,0.f,0.f},{0.f,0.f,0.f,0.f},{0.f,0.f,0.f,0.f}};
#pragma unroll
    for (int ks = 0; ks < 2; ks++)
#pragma unroll
        for (int ct = 0; ct < 3; ct++)
            acc[ct] = __builtin_amdgcn_mfma_f32_16x16x32_bf16(afrag[ks], bfrag[ks][ct], acc[ct], 0, 0, 0);

    float bcv[3];
#pragma unroll
    for (int ct = 0; ct < 3; ct++) bcv[ct] = cok[ct] ? bc[colv[ct]] : 0.f;

#pragma unroll
    for (int r = 0; r < 4; r++) {
        int node = base + lhi * 4 + r;
        bool ok = node < N;
        float lg[3];
#pragma unroll
        for (int ct = 0; ct < 3; ct++)
            lg[ct] = cok[ct] ? (acc[ct][r] + bcv[ct]) : -INFINITY;
        float m = fmaxf(fmaxf(lg[0], lg[1]), lg[2]);
#pragma unroll
        for (int off = 1; off < 16; off <<= 1) m = fmaxf(m, __shfl_xor(m, off));
        float ex = 0.f;
#pragma unroll
        for (int ct = 0; ct < 3; ct++) ex += cok[ct] ? __expf(lg[ct] - m) : 0.f;
#pragma unroll
        for (int off = 1; off < 16; off <<= 1) ex += __shfl_xor(ex, off);
        float ls = __logf(ex);
        if (ok) {
#pragma unroll
            for (int ct = 0; ct < 3; ct++)
                if (cok[ct]) out[(size_t)node * 40 + colv[ct]] = lg[ct] - m - ls;
        }
    }
}

// ---------------- launch ----------------

extern "C" void kernel_launch(void* const* d_in, const int* in_sizes, int n_in,
                              void* d_out, int out_size, void* d_ws, size_t ws_size,
                              hipStream_t stream) {
    const float* x   = (const float*)d_in[0];
    const void*  ei  = d_in[1];
    const float* W0  = (const float*)d_in[2];
    const float* as0 = (const float*)d_in[3];
    const float* ad0 = (const float*)d_in[4];
    const float* b0  = (const float*)d_in[5];
    const float* W1  = (const float*)d_in[6];
    const float* as1 = (const float*)d_in[7];
    const float* ad1 = (const float*)d_in[8];
    const float* b1  = (const float*)d_in[9];
    const float* Wc  = (const float*)d_in[10];
    const float* bc  = (const float*)d_in[11];
    float* out = (float*)d_out;

    const int N = in_sizes[0] / 128;   // 100000
    const int E = in_sizes[1] / 2;     // 1600000
    const int TOT = E + N;             // with self loops
    const int nbkt = (N + 127) / 128;  // dst buckets (128 nodes each)

    char* w = (char*)d_ws;
    unsigned short* HAbf    = (unsigned short*)w; w += (size_t)N * 64 * 2;  // gemm out (bf16)
    unsigned short* HCbf    = (unsigned short*)w; w += (size_t)N * 64 * 2;  // agg out (bf16)
    float*          Sv      = (float*)w;          w += (size_t)N * 4;
    float*          Dv      = (float*)w;          w += (size_t)N * 4;
    int*            rowptr  = (int*)w;            w += (size_t)(N + 1) * 4;
    int*            srcs    = (int*)w;            w += (size_t)TOT * 4;
    unsigned*       packed  = (unsigned*)w;       w += (size_t)nbkt * CAP * 4;  // fixed regions
    int*            gCursor = (int*)w;            w += NBKT_MAX * 4;
    int*            flag    = (int*)w;            w += 256;
    unsigned short* W0t     = (unsigned short*)w; w += 64 * 128 * 2;
    unsigned short* W1t     = (unsigned short*)w; w += 64 * 64 * 2;
    unsigned short* Wct     = (unsigned short*)w; w += 48 * 64 * 2;

    const int B = 256;
    const int gQuad  = (N + 15) / 16;            // agg: 4 nodes/wave x 4 waves/block
    const int gTile  = (N + 63) / 64;            // mfma: 64 rows per block
    const int nTileE = (TOT + TILE - 1) / TILE;  // edge tiles (4096)

    // ---- prep + CSR build (once; reused by both layers) ----
    prep_init<<<8, B, 0, stream>>>((const unsigned*)ei, flag, gCursor,
                                   W0, W1, Wc, W0t, W1t, Wct);
    bucket_scatter<<<nTileE, 1024, 0, stream>>>(ei, flag, gCursor, packed, E, N);
    bucket_finalize<<<nbkt, 512, 0, stream>>>(gCursor, packed, rowptr, srcs, N, TOT);

    // ---- layer 0 ----
    gemm_mfma<128, float><<<gTile, B, 0, stream>>>(x, W0t, as0, ad0, HAbf, Sv, Dv, N);
    gat_agg_q<<<gQuad, B, 0, stream>>>(rowptr, srcs, HAbf, Sv, Dv, b0, HCbf, N);

    // ---- layer 1 ----
    gemm_mfma<64, unsigned short><<<gTile, B, 0, stream>>>(HCbf, W1t, as1, ad1, HAbf, Sv, Dv, N);
    gat_agg_q<<<gQuad, B, 0, stream>>>(rowptr, srcs, HAbf, Sv, Dv, b1, HCbf, N);

    // ---- classifier + log_softmax (MFMA) ----
    classifier_mfma<<<gTile, B, 0, stream>>>(HCbf, Wct, bc, out, N);
}

// Round 23
// 171.085 us; speedup vs baseline: 1.0487x; 1.0349x over previous
//
#include <hip/hip_runtime.h>
#include <hip/hip_bf16.h>
#include <math.h>

typedef __attribute__((ext_vector_type(8))) short bf16x8;
typedef __attribute__((ext_vector_type(4))) float f32x4;

// ---------------- helpers ----------------

__device__ __forceinline__ short f2bf(float f) {           // RNE fp32->bf16
    unsigned u = __float_as_uint(f);
    u += 0x7fff + ((u >> 16) & 1);
    return (short)(u >> 16);
}
__device__ __forceinline__ float bf2f(unsigned short s) {
    return __uint_as_float(((unsigned)s) << 16);
}

__device__ __forceinline__ int load_idx(const void* ei, long long pos, int is64) {
    if (is64) return (int)((const long long*)ei)[pos];
    return ((const int*)ei)[pos];
}

// ================= CSR build via fixed-capacity bucket sort =================
// R16: random 4B stores = 110MB write-amp. R17: 8192-bitonic = 150us. R18/R20:
// counting-sort + per-node bitonic, reg-cached, no hist pass. R22: 128-node
// buckets + 512-thread finalize. Valid for N <= 131072. Here N = 100000.

#define TILE 4096
#define NBKT_MAX 1024
#define BKT_SH 7       // 128 nodes per bucket
#define CAP 6912       // per-bucket region; cnt ~ Poisson(2175), ~100 sigma

// fused one-time prep: cursor zeroing + dtype detect + weight transpose (bf16)
__global__ __launch_bounds__(256) void prep_init(
        const unsigned* __restrict__ ei, int* __restrict__ flag,
        int* __restrict__ gCursor,
        const float* __restrict__ W0, const float* __restrict__ W1,
        const float* __restrict__ Wc,
        unsigned short* __restrict__ W0t, unsigned short* __restrict__ W1t,
        unsigned short* __restrict__ Wct) {
    int t = (int)(blockIdx.x * (size_t)blockDim.x + threadIdx.x);
    int stride = (int)(gridDim.x * (size_t)blockDim.x);
    for (int i = t; i < NBKT_MAX; i += stride) gCursor[i] = 0;
    if (t == 0) {
        int ok = (ei[1] == 0u) & (ei[3] == 0u) & (ei[5] == 0u) &
                 (ei[7] == 0u) & (ei[9] == 0u) & (ei[11] == 0u);
        *flag = ok;
    }
    for (int i = t; i < 64 * 128; i += stride) {           // W0t[col][k], K=128
        int col = i >> 7, k = i & 127;
        W0t[i] = (unsigned short)f2bf(W0[k * 64 + col]);
    }
    for (int i = t; i < 64 * 64; i += stride) {            // W1t[col][k], K=64
        int col = i >> 6, k = i & 63;
        W1t[i] = (unsigned short)f2bf(W1[k * 64 + col]);
    }
    for (int i = t; i < 48 * 64; i += stride) {            // Wct[col][k], pad 40..47
        int col = i >> 6, k = i & 63;
        Wct[i] = (col < 40) ? (unsigned short)f2bf(Wc[k * 40 + col]) : 0;
    }
}

// per-tile: LDS hist+scan+rank, stage packed (d_local<<17|s) by bucket,
// one cursor atomic per bucket per tile, coalesced run writes into the
// bucket's FIXED region packed[b*CAP ...].
__global__ __launch_bounds__(1024) void bucket_scatter(
        const void* __restrict__ ei, const int* __restrict__ flag,
        int* __restrict__ gCursor, unsigned* __restrict__ packed, int E, int N) {
    __shared__ int h[NBKT_MAX], excl[NBKT_MAX], bse[NBKT_MAX], cur[NBKT_MAX];
    __shared__ unsigned pck[TILE];
    __shared__ int tgt[TILE];
    int tid = threadIdx.x;
    int is64 = *flag;
    int total = E + N;
    int base = blockIdx.x * TILE;

    h[tid] = 0;                     // NBKT_MAX == blockDim.x == 1024
    __syncthreads();

    int s[4], d[4];
    bool ok[4];
#pragma unroll
    for (int j = 0; j < 4; j++) {
        int t = base + j * 1024 + tid;
        ok[j] = t < total;
        if (ok[j]) {
            if (t < E) { s[j] = load_idx(ei, t, is64); d[j] = load_idx(ei, (long long)E + t, is64); }
            else       { s[j] = d[j] = t - E; }
            atomicAdd(&h[d[j] >> BKT_SH], 1);
        }
    }
    __syncthreads();
    excl[tid] = h[tid];
    __syncthreads();
    for (int off = 1; off < NBKT_MAX; off <<= 1) {
        int v = (tid >= off) ? excl[tid - off] : 0;
        __syncthreads();
        excl[tid] += v;
        __syncthreads();
    }
    excl[tid] -= h[tid];
    cur[tid] = excl[tid];
    bse[tid] = h[tid] ? atomicAdd(gCursor + tid, h[tid]) : 0;
    __syncthreads();
#pragma unroll
    for (int j = 0; j < 4; j++) {
        if (ok[j]) {
            int b = d[j] >> BKT_SH;
            int ls = atomicAdd(&cur[b], 1);
            pck[ls] = ((unsigned)(d[j] & 127) << 17) | (unsigned)s[j];
            int off = bse[b] + (ls - excl[b]);
            tgt[ls] = (off < CAP) ? (b * CAP + off) : -1;   // overflow guard (never fires)
        }
    }
    __syncthreads();
    int nvalid = total - base; if (nvalid > TILE) nvalid = TILE;
    for (int i = tid; i < nvalid; i += 1024)
        if (tgt[i] >= 0) packed[tgt[i]] = pck[i];
}

// per-bucket (512 threads): own bucketStart reduce; reg-cache packed (ONE
// global pass), hist+scan -> rowptr, group into LDS, canonical per-node sort.
__global__ __launch_bounds__(512) void bucket_finalize(
        const int* __restrict__ gCursor, const unsigned* __restrict__ packed,
        int* __restrict__ rowptr, int* __restrict__ srcs, int N, int TOT) {
    __shared__ unsigned arr2[CAP];     // grouped by node (src only)
    __shared__ int cnt2[128], sc[128], cur[128];
    __shared__ int red[512];
    int tid = threadIdx.x;
    int b = blockIdx.x;

    // bucketStart[b] = sum_{i<b} min(gCursor[i], CAP)
    int accs = 0;
    for (int i = tid; i < b; i += 512) {
        int c = gCursor[i];
        accs += (c > CAP ? CAP : c);
    }
    red[tid] = accs;
    __syncthreads();
    for (int off = 256; off > 0; off >>= 1) {
        if (tid < off) red[tid] += red[tid + off];
        __syncthreads();
    }
    int bs = red[0];
    int cnt = gCursor[b]; if (cnt > CAP) cnt = CAP;
    int nNodes = N - (b << BKT_SH); if (nNodes > 128) nNodes = 128;

    if (tid < 128) cnt2[tid] = 0;
    __syncthreads();

    // single global read into registers (<=14/thread)
    unsigned pv[14];
#pragma unroll
    for (int i = 0; i < 14; i++) {
        int idx = i * 512 + tid;
        if (idx < cnt) pv[i] = packed[(size_t)b * CAP + idx];
    }
#pragma unroll
    for (int i = 0; i < 14; i++) {
        int idx = i * 512 + tid;
        if (idx < cnt) atomicAdd(&cnt2[pv[i] >> 17], 1);
    }
    __syncthreads();
    // inclusive scan of 128 counts
    if (tid < 128) sc[tid] = cnt2[tid];
    __syncthreads();
    for (int off = 1; off < 128; off <<= 1) {
        int v = (tid < 128 && tid >= off) ? sc[tid - off] : 0;
        __syncthreads();
        if (tid < 128) sc[tid] += v;
        __syncthreads();
    }
    if (tid < 128) cur[tid] = sc[tid] - cnt2[tid];     // exclusive start
    if (tid < nNodes) rowptr[(b << BKT_SH) + tid] = bs + sc[tid] - cnt2[tid];
    if (b == 0 && tid == 0) rowptr[N] = TOT;
    __syncthreads();

    // group (order within segment racy; canonicalized by per-node sort)
#pragma unroll
    for (int i = 0; i < 14; i++) {
        int idx = i * 512 + tid;
        if (idx < cnt) {
            int pos = atomicAdd(&cur[pv[i] >> 17], 1);
            arr2[pos] = pv[i] & 0x1FFFFu;
        }
    }
    __syncthreads();

    int wid = tid >> 6, lane = tid & 63;               // 8 waves
    int half = lane >> 5, hl = lane & 31;
    // pass 1: deg<=32 nodes, 2 per wave (32-lane bitonic, 15 steps)
    for (int n2 = wid * 2; n2 < nNodes; n2 += 16) {
        int n = n2 + half;
        int deg = (n < nNodes) ? cnt2[n] : 0;
        if (deg >= 1 && deg <= 32) {
            int segs = sc[n] - deg;
            int v = (hl < deg) ? (int)arr2[segs + hl] : 0x7fffffff;
#pragma unroll
            for (int k = 2; k <= 32; k <<= 1) {
#pragma unroll
                for (int j = 16; j > 0; j >>= 1) {
                    if (j < k) {
                        int other = __shfl_xor(v, j);
                        bool dirDesc = (hl & k) != 0;
                        bool lower = (hl & j) == 0;
                        bool takeMin = (lower != dirDesc);
                        int mn = v < other ? v : other;
                        int mx = v < other ? other : v;
                        v = takeMin ? mn : mx;
                    }
                }
            }
            if (hl < deg) srcs[bs + segs + hl] = v;
        }
    }
    // pass 2: rare 32<deg<=64 (64-lane bitonic) and deg>64 (lane-0 insertion)
    for (int n = wid; n < nNodes; n += 8) {
        int deg = cnt2[n];
        if (deg <= 32) continue;
        int segs = sc[n] - deg;
        if (deg <= 64) {
            int v = (lane < deg) ? (int)arr2[segs + lane] : 0x7fffffff;
#pragma unroll
            for (int k = 2; k <= 64; k <<= 1) {
#pragma unroll
                for (int j = 32; j > 0; j >>= 1) {
                    if (j < k) {
                        int other = __shfl_xor(v, j);
                        bool dirDesc = (lane & k) != 0;
                        bool lower = (lane & j) == 0;
                        bool takeMin = (lower != dirDesc);
                        int mn = v < other ? v : other;
                        int mx = v < other ? other : v;
                        v = takeMin ? mn : mx;
                    }
                }
            }
            if (lane < deg) srcs[bs + segs + lane] = v;
        } else if (lane == 0) {
            for (int i = segs + 1; i < segs + deg; i++) {
                unsigned key = arr2[i];
                int j = i - 1;
                while (j >= segs && arr2[j] > key) { arr2[j + 1] = arr2[j]; j--; }
                arr2[j + 1] = key;
            }
            for (int i = 0; i < deg; i++) srcs[bs + segs + i] = (int)arr2[segs + i];
        }
    }
}

// ---------------- MFMA GEMM + attention scalars ----------------
// B-fragments from pre-transposed bf16 weights (Wt[col][k]).
// NO global-reduction atomics (R12 lesson: same-address atomicMax = ~155us drain).
template <int K, typename XT>
__global__ __launch_bounds__(256) void gemm_mfma(
        const XT* __restrict__ X, const unsigned short* __restrict__ Wt,
        const float* __restrict__ a_s, const float* __restrict__ a_d,
        unsigned short* __restrict__ Hbf,
        float* __restrict__ Sv, float* __restrict__ Dv, int N) {
    constexpr int KS = K / 32;
    int wid = threadIdx.x >> 6;
    int lane = threadIdx.x & 63;
    int base = blockIdx.x * 64 + wid * 16;
    if (base >= N) return;
    int l15 = lane & 15, lhi = lane >> 4;

    bf16x8 bfrag[KS][4];
#pragma unroll
    for (int ct = 0; ct < 4; ct++) {
        const unsigned short* wcol = Wt + (size_t)(ct * 16 + l15) * K + lhi * 8;
#pragma unroll
        for (int ks = 0; ks < KS; ks++)
            bfrag[ks][ct] = *(const bf16x8*)(wcol + ks * 32);
    }

    int row = base + l15; if (row >= N) row = N - 1;   // clamp; writes masked
    const XT* xr = X + (size_t)row * K + lhi * 8;
    bf16x8 afrag[KS];
#pragma unroll
    for (int ks = 0; ks < KS; ks++) {
        if constexpr (sizeof(XT) == 4) {
            float4 u0 = *(const float4*)(xr + ks * 32);
            float4 u1 = *(const float4*)(xr + ks * 32 + 4);
            afrag[ks][0] = f2bf(u0.x); afrag[ks][1] = f2bf(u0.y);
            afrag[ks][2] = f2bf(u0.z); afrag[ks][3] = f2bf(u0.w);
            afrag[ks][4] = f2bf(u1.x); afrag[ks][5] = f2bf(u1.y);
            afrag[ks][6] = f2bf(u1.z); afrag[ks][7] = f2bf(u1.w);
        } else {
            afrag[ks] = *(const bf16x8*)(xr + ks * 32);
        }
    }

    f32x4 acc[4] = {{0.f,0.f,0.f,0.f},{0.f,0.f,0.f,0.f},{0.f,0.f,0.f,0.f},{0.f,0.f,0.f,0.f}};
#pragma unroll
    for (int ks = 0; ks < KS; ks++)
#pragma unroll
        for (int ct = 0; ct < 4; ct++)
            acc[ct] = __builtin_amdgcn_mfma_f32_16x16x32_bf16(afrag[ks], bfrag[ks][ct], acc[ct], 0, 0, 0);

    float asv[4], adv[4];
#pragma unroll
    for (int ct = 0; ct < 4; ct++) { asv[ct] = a_s[ct * 16 + l15]; adv[ct] = a_d[ct * 16 + l15]; }

#pragma unroll
    for (int r = 0; r < 4; r++) {
        int grow = base + lhi * 4 + r;
        bool ok = grow < N;
        float sv = 0.f, dv = 0.f;
#pragma unroll
        for (int ct = 0; ct < 4; ct++) {
            float v = acc[ct][r];
            if (ok) Hbf[(size_t)grow * 64 + ct * 16 + l15] = (unsigned short)f2bf(v);
            sv = fmaf(v, asv[ct], sv);
            dv = fmaf(v, adv[ct], dv);
        }
#pragma unroll
        for (int off = 1; off < 16; off <<= 1) {
            sv += __shfl_xor(sv, off);
            dv += __shfl_xor(dv, off);
        }
        if (ok && l15 == 0) { Sv[grow] = sv; Dv[grow] = dv; }
    }
}

// ---------------- eighth-wave aggregation: 8 lanes/node, 8 channels/lane ----------------
// lane el = lane&7 owns channels 8el..8el+7 (ONE uint4 = 16B slice of the 128B row).
// 8 nodes per wave: half the load instructions and ~20% fewer VALU per edge vs
// quarter-wave. Per-channel & den accumulation order over sorted srcs is UNCHANGED
// -> bit-identical output to R22. M=0 shift (exact ratios, |e|<~10).
__global__ __launch_bounds__(256) void gat_agg_o(
        const int* __restrict__ rowptr, const int* __restrict__ srcs,
        const unsigned short* __restrict__ H, const float* __restrict__ Sv,
        const float* __restrict__ Dv, const float* __restrict__ b,
        unsigned short* __restrict__ OutRow, int N) {
    int wv = (int)((blockIdx.x * (size_t)blockDim.x + threadIdx.x) >> 6);
    int lane = threadIdx.x & 63;
    int g = lane >> 3, el = lane & 7;
    int node = wv * 8 + g;
    bool live = node < N;
    int start = 0, deg = 0;
    float dvv = 0.f;
    if (live) {
        start = rowptr[node];
        deg = rowptr[node + 1] - start;
        dvv = Dv[node];
    }

    const uint4* Hd = (const uint4*)H;            // 16B units: row = 8 x uint4
    float a0 = 0.f, a1 = 0.f, a2 = 0.f, a3 = 0.f,
          a4 = 0.f, a5 = 0.f, a6 = 0.f, a7 = 0.f, den = 0.f;

#define ACC8(p, h)                                                   \
    a0 = fmaf(p, __uint_as_float((h).x << 16), a0);                  \
    a1 = fmaf(p, __uint_as_float((h).x & 0xffff0000u), a1);          \
    a2 = fmaf(p, __uint_as_float((h).y << 16), a2);                  \
    a3 = fmaf(p, __uint_as_float((h).y & 0xffff0000u), a3);          \
    a4 = fmaf(p, __uint_as_float((h).z << 16), a4);                  \
    a5 = fmaf(p, __uint_as_float((h).z & 0xffff0000u), a5);          \
    a6 = fmaf(p, __uint_as_float((h).w << 16), a6);                  \
    a7 = fmaf(p, __uint_as_float((h).w & 0xffff0000u), a7);

    int j = 0;
    for (; j + 4 <= deg; j += 4) {
        int s0 = srcs[start + j], s1 = srcs[start + j + 1],
            s2 = srcs[start + j + 2], s3 = srcs[start + j + 3];
        float e0 = Sv[s0] + dvv, e1 = Sv[s1] + dvv,
              e2 = Sv[s2] + dvv, e3 = Sv[s3] + dvv;
        uint4 h0 = Hd[(size_t)s0 * 8 + el];
        uint4 h1 = Hd[(size_t)s1 * 8 + el];
        uint4 h2 = Hd[(size_t)s2 * 8 + el];
        uint4 h3 = Hd[(size_t)s3 * 8 + el];
        e0 = (e0 > 0.f) ? e0 : 0.2f * e0;
        e1 = (e1 > 0.f) ? e1 : 0.2f * e1;
        e2 = (e2 > 0.f) ? e2 : 0.2f * e2;
        e3 = (e3 > 0.f) ? e3 : 0.2f * e3;
        float p0 = __expf(e0), p1 = __expf(e1), p2 = __expf(e2), p3 = __expf(e3);
        den += (p0 + p1) + (p2 + p3);
        ACC8(p0, h0) ACC8(p1, h1) ACC8(p2, h2) ACC8(p3, h3)
    }
    for (; j < deg; j++) {
        int s0 = srcs[start + j];
        float e0 = Sv[s0] + dvv;
        uint4 h0 = Hd[(size_t)s0 * 8 + el];
        e0 = (e0 > 0.f) ? e0 : 0.2f * e0;
        float p0 = __expf(e0);
        den += p0;
        ACC8(p0, h0)
    }
#undef ACC8

    if (!live) return;
    float rden = 1.0f / (den + 1e-16f);
    float4 bb0 = *(const float4*)(b + el * 8);
    float4 bb1 = *(const float4*)(b + el * 8 + 4);
    float v0 = fmaf(a0, rden, bb0.x); v0 = v0 > 0.f ? v0 : 0.f;
    float v1 = fmaf(a1, rden, bb0.y); v1 = v1 > 0.f ? v1 : 0.f;
    float v2 = fmaf(a2, rden, bb0.z); v2 = v2 > 0.f ? v2 : 0.f;
    float v3 = fmaf(a3, rden, bb0.w); v3 = v3 > 0.f ? v3 : 0.f;
    float v4 = fmaf(a4, rden, bb1.x); v4 = v4 > 0.f ? v4 : 0.f;
    float v5 = fmaf(a5, rden, bb1.y); v5 = v5 > 0.f ? v5 : 0.f;
    float v6 = fmaf(a6, rden, bb1.z); v6 = v6 > 0.f ? v6 : 0.f;
    float v7 = fmaf(a7, rden, bb1.w); v7 = v7 > 0.f ? v7 : 0.f;
    uint4 pk;
    pk.x = ((unsigned)(unsigned short)f2bf(v1) << 16) | (unsigned short)f2bf(v0);
    pk.y = ((unsigned)(unsigned short)f2bf(v3) << 16) | (unsigned short)f2bf(v2);
    pk.z = ((unsigned)(unsigned short)f2bf(v5) << 16) | (unsigned short)f2bf(v4);
    pk.w = ((unsigned)(unsigned short)f2bf(v7) << 16) | (unsigned short)f2bf(v6);
    *(uint4*)(OutRow + (size_t)node * 64 + el * 8) = pk;
}

// ---------------- classifier via MFMA (pre-transposed bf16 Wct[48][64]) ----------------
__global__ __launch_bounds__(256) void classifier_mfma(
        const unsigned short* __restrict__ H, const unsigned short* __restrict__ Wct,
        const float* __restrict__ bc, float* __restrict__ out, int N) {
    int wid = threadIdx.x >> 6;
    int lane = threadIdx.x & 63;
    int base = blockIdx.x * 64 + wid * 16;
    if (base >= N) return;
    int l15 = lane & 15, lhi = lane >> 4;
    int colv[3]; bool cok[3];
#pragma unroll
    for (int ct = 0; ct < 3; ct++) { colv[ct] = ct * 16 + l15; cok[ct] = colv[ct] < 40; }

    bf16x8 bfrag[2][3];
#pragma unroll
    for (int ct = 0; ct < 3; ct++) {
        const unsigned short* wcol = Wct + (size_t)colv[ct] * 64 + lhi * 8;
#pragma unroll
        for (int ks = 0; ks < 2; ks++)
            bfrag[ks][ct] = *(const bf16x8*)(wcol + ks * 32);
    }

    int row = base + l15; if (row >= N) row = N - 1;   // clamp; writes masked
    const unsigned short* xr = H + (size_t)row * 64 + lhi * 8;
    bf16x8 afrag[2] = { *(const bf16x8*)xr, *(const bf16x8*)(xr + 32) };

    f32x4 acc[3] = {{0.f,0.f,0.f,0.f},{0.f,0.f,0.f,0.f},{0.f,0.f,0.f,0.f}};
#pragma unroll
    for (int ks = 0; ks < 2; ks++)
#pragma unroll
        for (int ct = 0; ct < 3; ct++)
            acc[ct] = __builtin_amdgcn_mfma_f32_16x16x32_bf16(afrag[ks], bfrag[ks][ct], acc[ct], 0, 0, 0);

    float bcv[3];
#pragma unroll
    for (int ct = 0; ct < 3; ct++) bcv[ct] = cok[ct] ? bc[colv[ct]] : 0.f;

#pragma unroll
    for (int r = 0; r < 4; r++) {
        int node = base + lhi * 4 + r;
        bool ok = node < N;
        float lg[3];
#pragma unroll
        for (int ct = 0; ct < 3; ct++)
            lg[ct] = cok[ct] ? (acc[ct][r] + bcv[ct]) : -INFINITY;
        float m = fmaxf(fmaxf(lg[0], lg[1]), lg[2]);
#pragma unroll
        for (int off = 1; off < 16; off <<= 1) m = fmaxf(m, __shfl_xor(m, off));
        float ex = 0.f;
#pragma unroll
        for (int ct = 0; ct < 3; ct++) ex += cok[ct] ? __expf(lg[ct] - m) : 0.f;
#pragma unroll
        for (int off = 1; off < 16; off <<= 1) ex += __shfl_xor(ex, off);
        float ls = __logf(ex);
        if (ok) {
#pragma unroll
            for (int ct = 0; ct < 3; ct++)
                if (cok[ct]) out[(size_t)node * 40 + colv[ct]] = lg[ct] - m - ls;
        }
    }
}

// ---------------- launch ----------------

extern "C" void kernel_launch(void* const* d_in, const int* in_sizes, int n_in,
                              void* d_out, int out_size, void* d_ws, size_t ws_size,
                              hipStream_t stream) {
    const float* x   = (const float*)d_in[0];
    const void*  ei  = d_in[1];
    const float* W0  = (const float*)d_in[2];
    const float* as0 = (const float*)d_in[3];
    const float* ad0 = (const float*)d_in[4];
    const float* b0  = (const float*)d_in[5];
    const float* W1  = (const float*)d_in[6];
    const float* as1 = (const float*)d_in[7];
    const float* ad1 = (const float*)d_in[8];
    const float* b1  = (const float*)d_in[9];
    const float* Wc  = (const float*)d_in[10];
    const float* bc  = (const float*)d_in[11];
    float* out = (float*)d_out;

    const int N = in_sizes[0] / 128;   // 100000
    const int E = in_sizes[1] / 2;     // 1600000
    const int TOT = E + N;             // with self loops
    const int nbkt = (N + 127) / 128;  // dst buckets (128 nodes each)

    char* w = (char*)d_ws;
    unsigned short* HAbf    = (unsigned short*)w; w += (size_t)N * 64 * 2;  // gemm out (bf16)
    unsigned short* HCbf    = (unsigned short*)w; w += (size_t)N * 64 * 2;  // agg out (bf16)
    float*          Sv      = (float*)w;          w += (size_t)N * 4;
    float*          Dv      = (float*)w;          w += (size_t)N * 4;
    int*            rowptr  = (int*)w;            w += (size_t)(N + 1) * 4;
    int*            srcs    = (int*)w;            w += (size_t)TOT * 4;
    unsigned*       packed  = (unsigned*)w;       w += (size_t)nbkt * CAP * 4;  // fixed regions
    int*            gCursor = (int*)w;            w += NBKT_MAX * 4;
    int*            flag    = (int*)w;            w += 256;
    unsigned short* W0t     = (unsigned short*)w; w += 64 * 128 * 2;
    unsigned short* W1t     = (unsigned short*)w; w += 64 * 64 * 2;
    unsigned short* Wct     = (unsigned short*)w; w += 48 * 64 * 2;

    const int B = 256;
    const int gOct   = (N + 31) / 32;            // agg: 8 nodes/wave x 4 waves/block
    const int gTile  = (N + 63) / 64;            // mfma: 64 rows per block
    const int nTileE = (TOT + TILE - 1) / TILE;  // edge tiles (4096)

    // ---- prep + CSR build (once; reused by both layers) ----
    prep_init<<<8, B, 0, stream>>>((const unsigned*)ei, flag, gCursor,
                                   W0, W1, Wc, W0t, W1t, Wct);
    bucket_scatter<<<nTileE, 1024, 0, stream>>>(ei, flag, gCursor, packed, E, N);
    bucket_finalize<<<nbkt, 512, 0, stream>>>(gCursor, packed, rowptr, srcs, N, TOT);

    // ---- layer 0 ----
    gemm_mfma<128, float><<<gTile, B, 0, stream>>>(x, W0t, as0, ad0, HAbf, Sv, Dv, N);
    gat_agg_o<<<gOct, B, 0, stream>>>(rowptr, srcs, HAbf, Sv, Dv, b0, HCbf, N);

    // ---- layer 1 ----
    gemm_mfma<64, unsigned short><<<gTile, B, 0, stream>>>(HCbf, W1t, as1, ad1, HAbf, Sv, Dv, N);
    gat_agg_o<<<gOct, B, 0, stream>>>(rowptr, srcs, HAbf, Sv, Dv, b1, HCbf, N);

    // ---- classifier + log_softmax (MFMA) ----
    classifier_mfma<<<gTile, B, 0, stream>>>(HCbf, Wct, bc, out, N);
}